// Round 10
// baseline (305.228 us; speedup 1.0000x reference)
//
#include <hip/hip_runtime.h>
#include <hip/hip_bf16.h>
#include <math.h>

#define NB 32          // graphs
#define N_PER 1000
#define TOTALN 32000
#define NE 512000
#define HID 128
#define Dh 64
#define NH 3
#define EPSV 1e-6f
#define PCH 25         // pool chunks per graph (40 nodes each)
#define W1CH 500       // k_w1 chunks (2 n's each)

typedef __attribute__((ext_vector_type(8))) short bf16x8;
typedef __attribute__((ext_vector_type(4))) float f32x4;

__device__ __forceinline__ float softplusf(float x) {
    return fmaxf(x, 0.0f) + log1pf(expf(-fabsf(x)));
}
__device__ __forceinline__ unsigned short f2b(float f) {
    __hip_bfloat16 h = __float2bfloat16(f);
    return __builtin_bit_cast(unsigned short, h);
}
__device__ __forceinline__ float b2f(unsigned short u) {
    unsigned int x = ((unsigned int)u) << 16;
    return __builtin_bit_cast(float, x);
}

__global__ __launch_bounds__(256) void k_init_deg(float* deg) {
    int i = blockIdx.x * 256 + threadIdx.x;
    if (i < TOTALN) deg[i] = 1.0f;   // self loop
}

__global__ __launch_bounds__(256) void k_deg(const int* __restrict__ ei, float* deg) {
    int e = blockIdx.x * 256 + threadIdx.x;
    if (e < NE) atomicAdd(&deg[ei[NE + e]], 1.0f);
}

__global__ __launch_bounds__(256) void k_prep(float* __restrict__ d, int* __restrict__ cnt) {
    int i = blockIdx.x * 256 + threadIdx.x;
    if (i < TOTALN) {
        float v = d[i];
        cnt[i] = (int)v - 1;
        d[i] = rsqrtf(v);
    }
}

__global__ __launch_bounds__(256) void k_scan_block(const int* __restrict__ cnt,
                                                    int* __restrict__ rowptr,
                                                    int* __restrict__ bsum) {
    __shared__ int sh[256];
    int t = threadIdx.x;
    int i = blockIdx.x * 256 + t;
    int v = cnt[i];
    sh[t] = v;
    __syncthreads();
    for (int off = 1; off < 256; off <<= 1) {
        int add = (t >= off) ? sh[t - off] : 0;
        __syncthreads();
        sh[t] += add;
        __syncthreads();
    }
    rowptr[i] = sh[t] - v;
    if (t == 255) bsum[blockIdx.x] = sh[255];
}

__global__ void k_scan_tot(int* __restrict__ bsum) {
    if (threadIdx.x == 0) {
        int run = 0;
        for (int i = 0; i < 125; ++i) { int t = bsum[i]; bsum[i] = run; run += t; }
    }
}

__global__ __launch_bounds__(256) void k_scan_add(int* __restrict__ rowptr,
                                                  const int* __restrict__ bsum,
                                                  int* __restrict__ cursor) {
    int i = blockIdx.x * 256 + threadIdx.x;
    int v = rowptr[i] + bsum[blockIdx.x];
    rowptr[i] = v;
    cursor[i] = v;
    if (i == 0) rowptr[TOTALN] = NE;
}

__global__ __launch_bounds__(256) void k_fill(const int* __restrict__ ei,
                                              const float* __restrict__ dinv,
                                              int* __restrict__ cursor,
                                              int* __restrict__ csr_src,
                                              float* __restrict__ csr_w) {
    int e = blockIdx.x * 256 + threadIdx.x;
    if (e < NE) {
        int s = ei[e], d = ei[NE + e];
        int pos = atomicAdd(&cursor[d], 1);
        csr_src[pos] = s;
        csr_w[pos] = dinv[s] * dinv[d];
    }
}

// transpose+convert W[128][128] f32 -> Wt[c][k] bf16
__global__ __launch_bounds__(256) void k_wcvt(const float* __restrict__ W,
                                              unsigned short* __restrict__ Wt) {
    int i = blockIdx.x * 256 + threadIdx.x;   // 16384
    int k = i >> 7, c = i & 127;
    Wt[c * 128 + k] = f2b(W[i]);
}

// Y[32000 x 128](bf16) = X[32000 x 128] @ W ; MFMA 16x16x32 bf16, no LDS.
template<int INF32>
__global__ __launch_bounds__(256) void k_mm(const void* __restrict__ Xv,
                                            const unsigned short* __restrict__ Wt,
                                            unsigned short* __restrict__ Y) {
    int tid = threadIdx.x;
    int wv = tid >> 6, l = tid & 63;
    int row0 = blockIdx.x * 64 + wv * 16;
    int r = l & 15, kc = l >> 4;
    bf16x8 a[4];
    if (INF32) {
        const float* X = (const float*)Xv;
#pragma unroll
        for (int ks = 0; ks < 4; ++ks) {
            const float* p = X + (long)(row0 + r) * 128 + ks * 32 + kc * 8;
            float4 f0 = *(const float4*)p;
            float4 f1 = *(const float4*)(p + 4);
            bf16x8 t;
            t[0] = (short)f2b(f0.x); t[1] = (short)f2b(f0.y);
            t[2] = (short)f2b(f0.z); t[3] = (short)f2b(f0.w);
            t[4] = (short)f2b(f1.x); t[5] = (short)f2b(f1.y);
            t[6] = (short)f2b(f1.z); t[7] = (short)f2b(f1.w);
            a[ks] = t;
        }
    } else {
        const unsigned short* X = (const unsigned short*)Xv;
#pragma unroll
        for (int ks = 0; ks < 4; ++ks)
            a[ks] = *(const bf16x8*)(X + (long)(row0 + r) * 128 + ks * 32 + kc * 8);
    }
    f32x4 acc[8];
#pragma unroll
    for (int nt = 0; nt < 8; ++nt) acc[nt] = (f32x4){0.f, 0.f, 0.f, 0.f};
#pragma unroll
    for (int ks = 0; ks < 4; ++ks) {
#pragma unroll
        for (int nt = 0; nt < 8; ++nt) {
            bf16x8 b = *(const bf16x8*)(Wt + (nt * 16 + r) * 128 + ks * 32 + kc * 8);
            acc[nt] = __builtin_amdgcn_mfma_f32_16x16x32_bf16(a[ks], b, acc[nt], 0, 0, 0);
        }
    }
#pragma unroll
    for (int nt = 0; nt < 8; ++nt)
#pragma unroll
        for (int j = 0; j < 4; ++j)
            Y[(long)(row0 + kc * 4 + j) * 128 + nt * 16 + r] = f2b(acc[nt][j]);
}

// CSR gather on bf16 features: 1 wave per node, 4B per lane, 8-deep edge ILP.
template<int MODE>
__global__ __launch_bounds__(256) void k_gather(const unsigned short* __restrict__ feat,
                                                unsigned short* __restrict__ out,
                                                const int* __restrict__ rowptr,
                                                const int* __restrict__ csr_src,
                                                const float* __restrict__ csr_w,
                                                const float* __restrict__ dinv,
                                                const float* __restrict__ bias) {
    int wid = threadIdx.x >> 6, lane = threadIdx.x & 63;
    int v = blockIdx.x * 4 + wid;
    const unsigned int* f2 = (const unsigned int*)feat;
    float dv = dinv[v];
    unsigned int sv = f2[v * 64 + lane];
    float acc0 = b2f((unsigned short)(sv & 0xffff)) * dv * dv;
    float acc1 = b2f((unsigned short)(sv >> 16)) * dv * dv;
    int e = rowptr[v], e1 = rowptr[v + 1];
    for (; e + 8 <= e1; e += 8) {
        unsigned int u[8];
        float w[8];
#pragma unroll
        for (int j = 0; j < 8; ++j) {
            int s = csr_src[e + j];
            w[j] = csr_w[e + j];
            u[j] = f2[s * 64 + lane];
        }
        float a0 = 0.f, a1 = 0.f, b0 = 0.f, b1 = 0.f;
#pragma unroll
        for (int j = 0; j < 4; ++j) {
            a0 += b2f((unsigned short)(u[j] & 0xffff)) * w[j];
            a1 += b2f((unsigned short)(u[j] >> 16)) * w[j];
            b0 += b2f((unsigned short)(u[j + 4] & 0xffff)) * w[j + 4];
            b1 += b2f((unsigned short)(u[j + 4] >> 16)) * w[j + 4];
        }
        acc0 += a0 + b0;
        acc1 += a1 + b1;
    }
    for (; e + 4 <= e1; e += 4) {
        unsigned int u[4];
        float w[4];
#pragma unroll
        for (int j = 0; j < 4; ++j) {
            int s = csr_src[e + j];
            w[j] = csr_w[e + j];
            u[j] = f2[s * 64 + lane];
        }
#pragma unroll
        for (int j = 0; j < 4; ++j) {
            acc0 += b2f((unsigned short)(u[j] & 0xffff)) * w[j];
            acc1 += b2f((unsigned short)(u[j] >> 16)) * w[j];
        }
    }
    for (; e < e1; ++e) {
        int s = csr_src[e];
        float w = csr_w[e];
        unsigned int u = f2[s * 64 + lane];
        acc0 += b2f((unsigned short)(u & 0xffff)) * w;
        acc1 += b2f((unsigned short)(u >> 16)) * w;
    }
    if (MODE == 0) {
        int c = lane * 2;
        acc0 = fmaxf(acc0 + bias[c], 0.f);
        acc1 = fmaxf(acc1 + bias[c + 1], 0.f);
    }
    ((unsigned int*)out)[v * 64 + lane] =
        (unsigned int)f2b(acc0) | ((unsigned int)f2b(acc1) << 16);
}

// pool stage 1 (bf16 input)
__global__ __launch_bounds__(256) void k_pool1(const unsigned short* __restrict__ A,
                                               float* __restrict__ pp) {
    __shared__ float sh[256];
    int b = blockIdx.x / PCH, ch = blockIdx.x % PCH;
    int c = threadIdx.x & 127, half = threadIdx.x >> 7;
    float acc = 0.f;
    int n0 = ch * 40;
#pragma unroll 4
    for (int j = half; j < 40; j += 2)
        acc += b2f(A[(long)(b * N_PER + n0 + j) * 128 + c]);
    sh[threadIdx.x] = acc;
    __syncthreads();
    if (threadIdx.x < 128)
        pp[blockIdx.x * 128 + c] = sh[c] + sh[128 + c];
}

__global__ __launch_bounds__(256) void k_pool2(const float* __restrict__ pp,
                                               const float* __restrict__ bias,
                                               float* __restrict__ hg,
                                               float* __restrict__ hgT) {
    int i = blockIdx.x * 256 + threadIdx.x;
    if (i >= NB * 128) return;
    int b = i >> 7, c = i & 127;
    float s = 0.f;
#pragma unroll
    for (int ch = 0; ch < PCH; ++ch)
        s += pp[(b * PCH + ch) * 128 + c];
    float v = s * (1.0f / N_PER) + bias[c];
    hg[i] = v;
    hgT[c * NB + b] = v;
}

// k_w1: block = (h, chunk of 2 n's); 256 threads = 4 waves = (nsub, khalf).
// 1500 blocks (~23 waves/CU), LDS 16KB, 8-deep Wg1 prefetch.
// hgT via contiguous s_loads; readfirstlane keeps k0 provably uniform.
__global__ __launch_bounds__(256) void k_w1(const float* __restrict__ hgT,
                                            const float* __restrict__ Wg1,
                                            const float* __restrict__ bg1,
                                            const float* __restrict__ actions,
                                            float* __restrict__ p1) {
    __shared__ float red[2][32][64];   // [nsub][b][d]
    int h = blockIdx.x / W1CH, chunk = blockIdx.x % W1CH;
    int tid = threadIdx.x;
    int wv = tid >> 6, d = tid & 63;
    int khalf = wv & 1, nsub = wv >> 1;
    int n = chunk * 2 + nsub;
    const long KS = (long)NH * N_PER * Dh;
    long col = (long)(h * N_PER + n) * Dh + d;
    const float* Wp = Wg1 + col;
    int k0 = __builtin_amdgcn_readfirstlane(khalf * 64);
    float acc[32];
#pragma unroll
    for (int b = 0; b < 32; ++b) acc[b] = 0.f;
    float4 c0, c1;
    c0.x = Wp[(long)(k0 + 0) * KS];
    c0.y = Wp[(long)(k0 + 1) * KS];
    c0.z = Wp[(long)(k0 + 2) * KS];
    c0.w = Wp[(long)(k0 + 3) * KS];
    c1.x = Wp[(long)(k0 + 4) * KS];
    c1.y = Wp[(long)(k0 + 5) * KS];
    c1.z = Wp[(long)(k0 + 6) * KS];
    c1.w = Wp[(long)(k0 + 7) * KS];
    for (int kk = 0; kk < 64; kk += 8) {
        int k = k0 + kk;
        float4 n0 = make_float4(0.f, 0.f, 0.f, 0.f);
        float4 n1 = make_float4(0.f, 0.f, 0.f, 0.f);
        if (kk + 8 < 64) {
            n0.x = Wp[(long)(k + 8) * KS];
            n0.y = Wp[(long)(k + 9) * KS];
            n0.z = Wp[(long)(k + 10) * KS];
            n0.w = Wp[(long)(k + 11) * KS];
            n1.x = Wp[(long)(k + 12) * KS];
            n1.y = Wp[(long)(k + 13) * KS];
            n1.z = Wp[(long)(k + 14) * KS];
            n1.w = Wp[(long)(k + 15) * KS];
        }
#pragma unroll
        for (int kq = 0; kq < 8; ++kq) {
            float w = (kq == 0) ? c0.x : (kq == 1) ? c0.y : (kq == 2) ? c0.z : (kq == 3) ? c0.w
                    : (kq == 4) ? c1.x : (kq == 5) ? c1.y : (kq == 6) ? c1.z : c1.w;
            const float* hp = hgT + (k + kq) * NB;   // uniform, contiguous 32 floats
#pragma unroll
            for (int b = 0; b < 32; ++b)
                acc[b] = fmaf(hp[b], w, acc[b]);
        }
        c0 = n0;
        c1 = n1;
    }
    // combine k-halves (pre-softplus)
    if (khalf == 0) {
#pragma unroll
        for (int b = 0; b < 32; ++b) red[nsub][b][d] = acc[b];
    }
    __syncthreads();
    if (khalf == 1) {
#pragma unroll
        for (int b = 0; b < 32; ++b) red[nsub][b][d] += acc[b];
    }
    __syncthreads();
    // softplus + action (one khalf-0 wave per n)
    if (khalf == 0) {
        float bgv = bg1[col];
#pragma unroll
        for (int b = 0; b < 32; ++b)
            red[nsub][b][d] = actions[b * N_PER + n] * softplusf(red[nsub][b][d] + bgv);
    }
    __syncthreads();
    // n-reduction (2 n's): 256 threads x 8 outputs
    const float* rf = &red[0][0][0];
    float* po = p1 + (long)(chunk * NH + h) * 2048;
#pragma unroll
    for (int j = 0; j < 8; ++j) {
        int o = j * 256 + tid;
        po[o] = rf[o] + rf[2048 + o];
    }
}

// block = (b,h): 96 blocks; thread = (part, d); 4-way chunk split + LDS finish
__global__ __launch_bounds__(256) void k_red1(const float* __restrict__ p1,
                                              float* __restrict__ h1) {
    __shared__ float sh[4][64];
    int b = blockIdx.x / 3, h = blockIdx.x % 3;
    int part = threadIdx.x >> 6, d = threadIdx.x & 63;
    float s = 0.f;
    for (int ch = part; ch < W1CH; ch += 4)
        s += p1[(long)(ch * 3 + h) * 2048 + b * 64 + d];
    if (part) sh[part][d] = s;
    __syncthreads();
    if (part == 0)
        h1[(b * 3 + h) * 64 + d] = sqrtf(fmaxf(s + sh[1][d] + sh[2][d] + sh[3][d], 0.f) + EPSV);
}

__global__ __launch_bounds__(256) void k_w2(const float* __restrict__ hg,
                                            const float* __restrict__ Wg2,
                                            const float* __restrict__ bg2,
                                            const float* __restrict__ h1,
                                            float* __restrict__ p2) {
    __shared__ float hgs[32][128];
    __shared__ float wt[128][64];
    __shared__ float h1s[32];
    int hd = blockIdx.x;
    int tid = threadIdx.x;
    for (int i = 0; i < 16; ++i) {
        int idx = tid + i * 256;
        hgs[idx >> 7][idx & 127] = hg[idx];
    }
    long base = (long)hd * 64;
    for (int i = 0; i < 32; ++i) {
        int idx = tid + i * 256;
        wt[idx >> 6][idx & 63] = Wg2[(long)(idx >> 6) * (NH * Dh * Dh) + base + (idx & 63)];
    }
    int h = hd >> 6, d = hd & 63;
    if (tid < 32) h1s[tid] = h1[tid * (NH * Dh) + h * Dh + d];
    __syncthreads();
    int e = tid & 63, bq = tid >> 6;
    float bgv = bg2[base + e];
    float dot[8];
#pragma unroll
    for (int bi = 0; bi < 8; ++bi) dot[bi] = 0.f;
    for (int k = 0; k < 128; ++k) {
        float w = wt[k][e];
#pragma unroll
        for (int bi = 0; bi < 8; ++bi)
            dot[bi] += hgs[bq * 8 + bi][k] * w;
    }
    float* po = p2 + (long)hd * (32 * 64);
#pragma unroll
    for (int bi = 0; bi < 8; ++bi) {
        int b = bq * 8 + bi;
        po[b * 64 + e] = softplusf(dot[bi] + bgv) * h1s[b];
    }
}

__global__ __launch_bounds__(256) void k_red2(const float* __restrict__ p2,
                                              float* __restrict__ h2) {
    int o = blockIdx.x * 256 + threadIdx.x;
    if (o >= 32 * 192) return;
    int bh = o >> 6;
    int h = bh % 3, b = bh / 3;
    int e = o & 63;
    float s = 0.f;
    for (int d = 0; d < 64; ++d)
        s += p2[(h * 64 + d) * 2048 + b * 64 + e];
    h2[o] = log1pf(fmaxf(s, 0.f));
}

__global__ __launch_bounds__(192) void k_out(const float* __restrict__ hg,
                                             const float* __restrict__ Wg3,
                                             const float* __restrict__ bg3,
                                             const float* __restrict__ h2,
                                             float* __restrict__ out) {
    __shared__ float hgb[128];
    __shared__ float hres[NH];
    int b = blockIdx.x, tid = threadIdx.x;
    if (tid < 128) hgb[tid] = hg[b * 128 + tid];
    __syncthreads();
    int h = tid / 64, e = tid & 63;
    int c = h * 64 + e;
    float dot = 0.f;
    for (int k = 0; k < 128; ++k)
        dot += hgb[k] * Wg3[k * (NH * Dh) + c];
    float v = softplusf(dot + bg3[c]) * h2[b * 192 + c];
    for (int off = 32; off; off >>= 1)
        v += __shfl_down(v, off, 64);
    if (e == 0) hres[h] = v;
    __syncthreads();
    if (tid == 0) out[b] = fminf(fminf(hres[0], hres[1]), hres[2]);
}

extern "C" void kernel_launch(void* const* d_in, const int* in_sizes, int n_in,
                              void* d_out, int out_size, void* d_ws, size_t ws_size,
                              hipStream_t stream) {
    const float* x   = (const float*)d_in[0];
    const int*   ei  = (const int*)d_in[1];
    const float* act = (const float*)d_in[3];
    const float* Wc1 = (const float*)d_in[4];
    const float* bc1 = (const float*)d_in[5];
    const float* Wc2 = (const float*)d_in[6];
    const float* bc2 = (const float*)d_in[7];
    const float* Wc3 = (const float*)d_in[8];
    const float* bc3 = (const float*)d_in[9];
    const float* Wg1 = (const float*)d_in[10];
    const float* bg1 = (const float*)d_in[11];
    const float* Wg2 = (const float*)d_in[12];
    const float* bg2 = (const float*)d_in[13];
    const float* Wg3 = (const float*)d_in[14];
    const float* bg3 = (const float*)d_in[15];
    float* out = (float*)d_out;

    float* ws   = (float*)d_ws;
    float* dinv = ws;                               // 32000
    float* bufA = dinv + TOTALN;                    // feat A (bf16 lives here)
    float* bufB = bufA + (long)TOTALN * 128;        // feat B / p1 alias
    float* hg   = bufB + (long)TOTALN * 128;        // 4096
    float* h1   = hg + 32 * 128;                    // 6144
    float* h2   = h1 + 32 * 192;                    // 6144
    float* csr_w = h2 + 32 * 192;                   // 512000
    float* pp   = csr_w + NE;                       // 102400
    float* hgT  = pp + NB * PCH * 128;              // 4096
    int* cnt    = (int*)(hgT + 128 * NB);           // 32000
    int* rowptr = cnt + TOTALN;                     // 32001 (+3 pad)
    int* cursor = rowptr + TOTALN + 4;              // 32000
    int* bsum   = cursor + TOTALN;                  // 128
    int* csr_src= bsum + 128;                       // 512000
    unsigned short* Wt = (unsigned short*)(csr_src + NE);  // 16384 bf16
    unsigned short* fA = (unsigned short*)bufA;
    unsigned short* fB = (unsigned short*)bufB;
    float* p1   = bufB;                             // 500*3*2048 = 12.3MB <= 16.4MB
    float* p2   = bufA;                             // free after pool1

    // degree + norm + CSR build
    k_init_deg<<<(TOTALN + 255) / 256, 256, 0, stream>>>(dinv);
    k_deg<<<NE / 256, 256, 0, stream>>>(ei, dinv);
    k_prep<<<(TOTALN + 255) / 256, 256, 0, stream>>>(dinv, cnt);
    k_scan_block<<<125, 256, 0, stream>>>(cnt, rowptr, bsum);
    k_scan_tot<<<1, 64, 0, stream>>>(bsum);
    k_scan_add<<<125, 256, 0, stream>>>(rowptr, bsum, cursor);
    k_fill<<<NE / 256, 256, 0, stream>>>(ei, dinv, cursor, csr_src, csr_w);

    // layer 1 (x f32 -> bf16 MFMA)
    k_wcvt<<<64, 256, 0, stream>>>(Wc1, Wt);
    k_mm<1><<<500, 256, 0, stream>>>(x, Wt, fB);
    k_gather<0><<<TOTALN / 4, 256, 0, stream>>>(fB, fA, rowptr, csr_src, csr_w, dinv, bc1);
    // layer 2
    k_wcvt<<<64, 256, 0, stream>>>(Wc2, Wt);
    k_mm<0><<<500, 256, 0, stream>>>(fA, Wt, fB);
    k_gather<0><<<TOTALN / 4, 256, 0, stream>>>(fB, fA, rowptr, csr_src, csr_w, dinv, bc2);
    // layer 3 (no relu; bias folded into pool stage 2)
    k_wcvt<<<64, 256, 0, stream>>>(Wc3, Wt);
    k_mm<0><<<500, 256, 0, stream>>>(fA, Wt, fB);
    k_gather<1><<<TOTALN / 4, 256, 0, stream>>>(fB, fA, rowptr, csr_src, csr_w, dinv, nullptr);
    k_pool1<<<NB * PCH, 256, 0, stream>>>(fA, pp);
    k_pool2<<<(NB * 128 + 255) / 256, 256, 0, stream>>>(pp, bc3, hg, hgT);

    // hypernetwork + compute_q
    k_w1<<<NH * W1CH, 256, 0, stream>>>(hgT, Wg1, bg1, act, p1);
    k_red1<<<96, 256, 0, stream>>>(p1, h1);
    k_w2<<<NH * Dh, 256, 0, stream>>>(hg, Wg2, bg2, h1, p2);
    k_red2<<<24, 256, 0, stream>>>(p2, h2);
    k_out<<<NB, 192, 0, stream>>>(hg, Wg3, bg3, h2, out);
}

// Round 11
// 284.220 us; speedup vs baseline: 1.0739x; 1.0739x over previous
//
#include <hip/hip_runtime.h>
#include <hip/hip_bf16.h>
#include <math.h>

#define NB 32          // graphs
#define N_PER 1000
#define TOTALN 32000
#define NE 512000
#define HID 128
#define Dh 64
#define NH 3
#define EPSV 1e-6f
#define PCH 25         // pool chunks per graph (40 nodes each)
#define W1CH 250       // k_w1 chunks (4 n's each)

typedef __attribute__((ext_vector_type(8))) short bf16x8;
typedef __attribute__((ext_vector_type(4))) float f32x4;

__device__ __forceinline__ float softplusf(float x) {
    return fmaxf(x, 0.0f) + log1pf(expf(-fabsf(x)));
}
__device__ __forceinline__ unsigned short f2b(float f) {
    __hip_bfloat16 h = __float2bfloat16(f);
    return __builtin_bit_cast(unsigned short, h);
}
__device__ __forceinline__ float b2f(unsigned short u) {
    unsigned int x = ((unsigned int)u) << 16;
    return __builtin_bit_cast(float, x);
}

__global__ __launch_bounds__(256) void k_init_deg(float* deg) {
    int i = blockIdx.x * 256 + threadIdx.x;
    if (i < TOTALN) deg[i] = 1.0f;   // self loop
}

__global__ __launch_bounds__(256) void k_deg(const int* __restrict__ ei, float* deg) {
    int e = blockIdx.x * 256 + threadIdx.x;
    if (e < NE) atomicAdd(&deg[ei[NE + e]], 1.0f);
}

__global__ __launch_bounds__(256) void k_prep(float* __restrict__ d, int* __restrict__ cnt) {
    int i = blockIdx.x * 256 + threadIdx.x;
    if (i < TOTALN) {
        float v = d[i];
        cnt[i] = (int)v - 1;
        d[i] = rsqrtf(v);
    }
}

__global__ __launch_bounds__(256) void k_scan_block(const int* __restrict__ cnt,
                                                    int* __restrict__ rowptr,
                                                    int* __restrict__ bsum) {
    __shared__ int sh[256];
    int t = threadIdx.x;
    int i = blockIdx.x * 256 + t;
    int v = cnt[i];
    sh[t] = v;
    __syncthreads();
    for (int off = 1; off < 256; off <<= 1) {
        int add = (t >= off) ? sh[t - off] : 0;
        __syncthreads();
        sh[t] += add;
        __syncthreads();
    }
    rowptr[i] = sh[t] - v;
    if (t == 255) bsum[blockIdx.x] = sh[255];
}

__global__ void k_scan_tot(int* __restrict__ bsum) {
    if (threadIdx.x == 0) {
        int run = 0;
        for (int i = 0; i < 125; ++i) { int t = bsum[i]; bsum[i] = run; run += t; }
    }
}

__global__ __launch_bounds__(256) void k_scan_add(int* __restrict__ rowptr,
                                                  const int* __restrict__ bsum,
                                                  int* __restrict__ cursor) {
    int i = blockIdx.x * 256 + threadIdx.x;
    int v = rowptr[i] + bsum[blockIdx.x];
    rowptr[i] = v;
    cursor[i] = v;
    if (i == 0) rowptr[TOTALN] = NE;
}

__global__ __launch_bounds__(256) void k_fill(const int* __restrict__ ei,
                                              const float* __restrict__ dinv,
                                              int* __restrict__ cursor,
                                              int* __restrict__ csr_src,
                                              float* __restrict__ csr_w) {
    int e = blockIdx.x * 256 + threadIdx.x;
    if (e < NE) {
        int s = ei[e], d = ei[NE + e];
        int pos = atomicAdd(&cursor[d], 1);
        csr_src[pos] = s;
        csr_w[pos] = dinv[s] * dinv[d];
    }
}

// transpose+convert W[128][128] f32 -> Wt[c][k] bf16
__global__ __launch_bounds__(256) void k_wcvt(const float* __restrict__ W,
                                              unsigned short* __restrict__ Wt) {
    int i = blockIdx.x * 256 + threadIdx.x;   // 16384
    int k = i >> 7, c = i & 127;
    Wt[c * 128 + k] = f2b(W[i]);
}

// Y[32000 x 128](bf16) = X[32000 x 128] @ W ; MFMA 16x16x32 bf16, no LDS.
template<int INF32>
__global__ __launch_bounds__(256) void k_mm(const void* __restrict__ Xv,
                                            const unsigned short* __restrict__ Wt,
                                            unsigned short* __restrict__ Y) {
    int tid = threadIdx.x;
    int wv = tid >> 6, l = tid & 63;
    int row0 = blockIdx.x * 64 + wv * 16;
    int r = l & 15, kc = l >> 4;
    bf16x8 a[4];
    if (INF32) {
        const float* X = (const float*)Xv;
#pragma unroll
        for (int ks = 0; ks < 4; ++ks) {
            const float* p = X + (long)(row0 + r) * 128 + ks * 32 + kc * 8;
            float4 f0 = *(const float4*)p;
            float4 f1 = *(const float4*)(p + 4);
            bf16x8 t;
            t[0] = (short)f2b(f0.x); t[1] = (short)f2b(f0.y);
            t[2] = (short)f2b(f0.z); t[3] = (short)f2b(f0.w);
            t[4] = (short)f2b(f1.x); t[5] = (short)f2b(f1.y);
            t[6] = (short)f2b(f1.z); t[7] = (short)f2b(f1.w);
            a[ks] = t;
        }
    } else {
        const unsigned short* X = (const unsigned short*)Xv;
#pragma unroll
        for (int ks = 0; ks < 4; ++ks)
            a[ks] = *(const bf16x8*)(X + (long)(row0 + r) * 128 + ks * 32 + kc * 8);
    }
    f32x4 acc[8];
#pragma unroll
    for (int nt = 0; nt < 8; ++nt) acc[nt] = (f32x4){0.f, 0.f, 0.f, 0.f};
#pragma unroll
    for (int ks = 0; ks < 4; ++ks) {
#pragma unroll
        for (int nt = 0; nt < 8; ++nt) {
            bf16x8 b = *(const bf16x8*)(Wt + (nt * 16 + r) * 128 + ks * 32 + kc * 8);
            acc[nt] = __builtin_amdgcn_mfma_f32_16x16x32_bf16(a[ks], b, acc[nt], 0, 0, 0);
        }
    }
#pragma unroll
    for (int nt = 0; nt < 8; ++nt)
#pragma unroll
        for (int j = 0; j < 4; ++j)
            Y[(long)(row0 + kc * 4 + j) * 128 + nt * 16 + r] = f2b(acc[nt][j]);
}

// CSR gather on bf16 features (R9 version): 1 wave per node, 4B per lane, 4-deep ILP.
template<int MODE>
__global__ __launch_bounds__(256) void k_gather(const unsigned short* __restrict__ feat,
                                                unsigned short* __restrict__ out,
                                                const int* __restrict__ rowptr,
                                                const int* __restrict__ csr_src,
                                                const float* __restrict__ csr_w,
                                                const float* __restrict__ dinv,
                                                const float* __restrict__ bias) {
    int wid = threadIdx.x >> 6, lane = threadIdx.x & 63;
    int v = blockIdx.x * 4 + wid;
    const unsigned int* f2 = (const unsigned int*)feat;
    float dv = dinv[v];
    unsigned int sv = f2[v * 64 + lane];
    float acc0 = b2f((unsigned short)(sv & 0xffff)) * dv * dv;
    float acc1 = b2f((unsigned short)(sv >> 16)) * dv * dv;
    int e = rowptr[v], e1 = rowptr[v + 1];
    for (; e + 4 <= e1; e += 4) {
        int s0 = csr_src[e], s1 = csr_src[e + 1], s2 = csr_src[e + 2], s3 = csr_src[e + 3];
        float w0 = csr_w[e], w1 = csr_w[e + 1], w2 = csr_w[e + 2], w3 = csr_w[e + 3];
        unsigned int u0 = f2[s0 * 64 + lane];
        unsigned int u1 = f2[s1 * 64 + lane];
        unsigned int u2 = f2[s2 * 64 + lane];
        unsigned int u3 = f2[s3 * 64 + lane];
        acc0 += b2f((unsigned short)(u0 & 0xffff)) * w0 + b2f((unsigned short)(u1 & 0xffff)) * w1
              + b2f((unsigned short)(u2 & 0xffff)) * w2 + b2f((unsigned short)(u3 & 0xffff)) * w3;
        acc1 += b2f((unsigned short)(u0 >> 16)) * w0 + b2f((unsigned short)(u1 >> 16)) * w1
              + b2f((unsigned short)(u2 >> 16)) * w2 + b2f((unsigned short)(u3 >> 16)) * w3;
    }
    for (; e < e1; ++e) {
        int s = csr_src[e];
        float w = csr_w[e];
        unsigned int u = f2[s * 64 + lane];
        acc0 += b2f((unsigned short)(u & 0xffff)) * w;
        acc1 += b2f((unsigned short)(u >> 16)) * w;
    }
    if (MODE == 0) {
        int c = lane * 2;
        acc0 = fmaxf(acc0 + bias[c], 0.f);
        acc1 = fmaxf(acc1 + bias[c + 1], 0.f);
    }
    ((unsigned int*)out)[v * 64 + lane] =
        (unsigned int)f2b(acc0) | ((unsigned int)f2b(acc1) << 16);
}

// pool stage 1 (bf16 input)
__global__ __launch_bounds__(256) void k_pool1(const unsigned short* __restrict__ A,
                                               float* __restrict__ pp) {
    __shared__ float sh[256];
    int b = blockIdx.x / PCH, ch = blockIdx.x % PCH;
    int c = threadIdx.x & 127, half = threadIdx.x >> 7;
    float acc = 0.f;
    int n0 = ch * 40;
#pragma unroll 4
    for (int j = half; j < 40; j += 2)
        acc += b2f(A[(long)(b * N_PER + n0 + j) * 128 + c]);
    sh[threadIdx.x] = acc;
    __syncthreads();
    if (threadIdx.x < 128)
        pp[blockIdx.x * 128 + c] = sh[c] + sh[128 + c];
}

// pool stage 2: mean + layer-3 bias; writes hg (f32), hgT (f32) and hgB (bf16)
__global__ __launch_bounds__(256) void k_pool2(const float* __restrict__ pp,
                                               const float* __restrict__ bias,
                                               float* __restrict__ hg,
                                               float* __restrict__ hgT,
                                               unsigned short* __restrict__ hgB) {
    int i = blockIdx.x * 256 + threadIdx.x;
    if (i >= NB * 128) return;
    int b = i >> 7, c = i & 127;
    float s = 0.f;
#pragma unroll
    for (int ch = 0; ch < PCH; ++ch)
        s += pp[(b * PCH + ch) * 128 + c];
    float v = s * (1.0f / N_PER) + bias[c];
    hg[i] = v;
    hgT[c * NB + b] = v;
    hgB[i] = f2b(v);
}

// k_w1 (MFMA): block = (h, chunk of 4 n); wave = one n (64 d-cols).
// C[32 b x 64 d] = hg[32x128] @ Wg1[:, h,n,:] via 2 mt x 4 ct x 4 ks mfma_16x16x32.
// A = hgB bf16 (L2-hot); B = Wg1 f32 loaded direct (8 strided dwords/frag) + inline cvt.
// Frag mapping identical to k_mm (on-device verified): A row=l&15, k-chunk=(l>>4)*8;
// D: row(M)=kc*4+j, col(N)=ct*16+r.
__global__ __launch_bounds__(256) void k_w1(const unsigned short* __restrict__ hgB,
                                            const float* __restrict__ Wg1,
                                            const float* __restrict__ bg1,
                                            const float* __restrict__ actions,
                                            float* __restrict__ p1) {
    __shared__ float red[32][65];   // padded vs bank conflicts
    int h = blockIdx.x / W1CH, chunk = blockIdx.x % W1CH;
    int tid = threadIdx.x;
    int wv = tid >> 6, l = tid & 63;
    int r = l & 15, kc = l >> 4;
    int n = chunk * 4 + wv;
    const long KS = (long)NH * N_PER * Dh;            // 192000
    long colbase = (long)h * (N_PER * Dh) + (long)n * Dh;
    // A frags
    bf16x8 a[2][4];
#pragma unroll
    for (int mt = 0; mt < 2; ++mt)
#pragma unroll
        for (int ks = 0; ks < 4; ++ks)
            a[mt][ks] = *(const bf16x8*)(hgB + (mt * 16 + r) * 128 + ks * 32 + kc * 8);
    f32x4 acc[2][4];
#pragma unroll
    for (int mt = 0; mt < 2; ++mt)
#pragma unroll
        for (int ct = 0; ct < 4; ++ct) acc[mt][ct] = (f32x4){0.f, 0.f, 0.f, 0.f};
#pragma unroll
    for (int ct = 0; ct < 4; ++ct) {
        const float* Wp = Wg1 + colbase + ct * 16 + r;
#pragma unroll
        for (int ks = 0; ks < 4; ++ks) {
            int kb = ks * 32 + kc * 8;
            float f0 = Wp[(long)(kb + 0) * KS];
            float f1 = Wp[(long)(kb + 1) * KS];
            float f2v = Wp[(long)(kb + 2) * KS];
            float f3 = Wp[(long)(kb + 3) * KS];
            float f4 = Wp[(long)(kb + 4) * KS];
            float f5 = Wp[(long)(kb + 5) * KS];
            float f6 = Wp[(long)(kb + 6) * KS];
            float f7 = Wp[(long)(kb + 7) * KS];
            bf16x8 bb;
            bb[0] = (short)f2b(f0); bb[1] = (short)f2b(f1);
            bb[2] = (short)f2b(f2v); bb[3] = (short)f2b(f3);
            bb[4] = (short)f2b(f4); bb[5] = (short)f2b(f5);
            bb[6] = (short)f2b(f6); bb[7] = (short)f2b(f7);
            acc[0][ct] = __builtin_amdgcn_mfma_f32_16x16x32_bf16(a[0][ks], bb, acc[0][ct], 0, 0, 0);
            acc[1][ct] = __builtin_amdgcn_mfma_f32_16x16x32_bf16(a[1][ks], bb, acc[1][ct], 0, 0, 0);
        }
    }
    // epilogue: softplus(+bg1) * action, then 4-phase n-sum in LDS
    float actv[2][4];
#pragma unroll
    for (int mt = 0; mt < 2; ++mt)
#pragma unroll
        for (int j = 0; j < 4; ++j)
            actv[mt][j] = actions[(mt * 16 + kc * 4 + j) * N_PER + n];
    float bgv[4];
#pragma unroll
    for (int ct = 0; ct < 4; ++ct)
        bgv[ct] = bg1[colbase + ct * 16 + r];
    float sp[2][4][4];
#pragma unroll
    for (int mt = 0; mt < 2; ++mt)
#pragma unroll
        for (int ct = 0; ct < 4; ++ct)
#pragma unroll
            for (int j = 0; j < 4; ++j)
                sp[mt][ct][j] = softplusf(acc[mt][ct][j] + bgv[ct]) * actv[mt][j];
#pragma unroll
    for (int ph = 0; ph < 4; ++ph) {
        if (wv == ph) {
#pragma unroll
            for (int mt = 0; mt < 2; ++mt)
#pragma unroll
                for (int ct = 0; ct < 4; ++ct)
#pragma unroll
                    for (int j = 0; j < 4; ++j) {
                        int b = mt * 16 + kc * 4 + j;
                        int d = ct * 16 + r;
                        if (ph == 0) red[b][d] = sp[mt][ct][j];
                        else red[b][d] += sp[mt][ct][j];
                    }
        }
        __syncthreads();
    }
    float* po = p1 + (long)(chunk * NH + h) * 2048;
#pragma unroll
    for (int j2 = 0; j2 < 8; ++j2) {
        int o = j2 * 256 + tid;
        po[o] = red[o >> 6][o & 63];
    }
}

// block = (b,h): 96 blocks; thread = (part, d); 4-way chunk split + LDS finish
__global__ __launch_bounds__(256) void k_red1(const float* __restrict__ p1,
                                              float* __restrict__ h1) {
    __shared__ float sh[4][64];
    int b = blockIdx.x / 3, h = blockIdx.x % 3;
    int part = threadIdx.x >> 6, d = threadIdx.x & 63;
    float s = 0.f;
    for (int ch = part; ch < W1CH; ch += 4)
        s += p1[(long)(ch * 3 + h) * 2048 + b * 64 + d];
    if (part) sh[part][d] = s;
    __syncthreads();
    if (part == 0)
        h1[(b * 3 + h) * 64 + d] = sqrtf(fmaxf(s + sh[1][d] + sh[2][d] + sh[3][d], 0.f) + EPSV);
}

__global__ __launch_bounds__(256) void k_w2(const float* __restrict__ hg,
                                            const float* __restrict__ Wg2,
                                            const float* __restrict__ bg2,
                                            const float* __restrict__ h1,
                                            float* __restrict__ p2) {
    __shared__ float hgs[32][128];
    __shared__ float wt[128][64];
    __shared__ float h1s[32];
    int hd = blockIdx.x;
    int tid = threadIdx.x;
    for (int i = 0; i < 16; ++i) {
        int idx = tid + i * 256;
        hgs[idx >> 7][idx & 127] = hg[idx];
    }
    long base = (long)hd * 64;
    for (int i = 0; i < 32; ++i) {
        int idx = tid + i * 256;
        wt[idx >> 6][idx & 63] = Wg2[(long)(idx >> 6) * (NH * Dh * Dh) + base + (idx & 63)];
    }
    int h = hd >> 6, d = hd & 63;
    if (tid < 32) h1s[tid] = h1[tid * (NH * Dh) + h * Dh + d];
    __syncthreads();
    int e = tid & 63, bq = tid >> 6;
    float bgv = bg2[base + e];
    float dot[8];
#pragma unroll
    for (int bi = 0; bi < 8; ++bi) dot[bi] = 0.f;
    for (int k = 0; k < 128; ++k) {
        float w = wt[k][e];
#pragma unroll
        for (int bi = 0; bi < 8; ++bi)
            dot[bi] += hgs[bq * 8 + bi][k] * w;
    }
    float* po = p2 + (long)hd * (32 * 64);
#pragma unroll
    for (int bi = 0; bi < 8; ++bi) {
        int b = bq * 8 + bi;
        po[b * 64 + e] = softplusf(dot[bi] + bgv) * h1s[b];
    }
}

__global__ __launch_bounds__(256) void k_red2(const float* __restrict__ p2,
                                              float* __restrict__ h2) {
    int o = blockIdx.x * 256 + threadIdx.x;
    if (o >= 32 * 192) return;
    int bh = o >> 6;
    int h = bh % 3, b = bh / 3;
    int e = o & 63;
    float s = 0.f;
    for (int d = 0; d < 64; ++d)
        s += p2[(h * 64 + d) * 2048 + b * 64 + e];
    h2[o] = log1pf(fmaxf(s, 0.f));
}

__global__ __launch_bounds__(192) void k_out(const float* __restrict__ hg,
                                             const float* __restrict__ Wg3,
                                             const float* __restrict__ bg3,
                                             const float* __restrict__ h2,
                                             float* __restrict__ out) {
    __shared__ float hgb[128];
    __shared__ float hres[NH];
    int b = blockIdx.x, tid = threadIdx.x;
    if (tid < 128) hgb[tid] = hg[b * 128 + tid];
    __syncthreads();
    int h = tid / 64, e = tid & 63;
    int c = h * 64 + e;
    float dot = 0.f;
    for (int k = 0; k < 128; ++k)
        dot += hgb[k] * Wg3[k * (NH * Dh) + c];
    float v = softplusf(dot + bg3[c]) * h2[b * 192 + c];
    for (int off = 32; off; off >>= 1)
        v += __shfl_down(v, off, 64);
    if (e == 0) hres[h] = v;
    __syncthreads();
    if (tid == 0) out[b] = fminf(fminf(hres[0], hres[1]), hres[2]);
}

extern "C" void kernel_launch(void* const* d_in, const int* in_sizes, int n_in,
                              void* d_out, int out_size, void* d_ws, size_t ws_size,
                              hipStream_t stream) {
    const float* x   = (const float*)d_in[0];
    const int*   ei  = (const int*)d_in[1];
    const float* act = (const float*)d_in[3];
    const float* Wc1 = (const float*)d_in[4];
    const float* bc1 = (const float*)d_in[5];
    const float* Wc2 = (const float*)d_in[6];
    const float* bc2 = (const float*)d_in[7];
    const float* Wc3 = (const float*)d_in[8];
    const float* bc3 = (const float*)d_in[9];
    const float* Wg1 = (const float*)d_in[10];
    const float* bg1 = (const float*)d_in[11];
    const float* Wg2 = (const float*)d_in[12];
    const float* bg2 = (const float*)d_in[13];
    const float* Wg3 = (const float*)d_in[14];
    const float* bg3 = (const float*)d_in[15];
    float* out = (float*)d_out;

    float* ws   = (float*)d_ws;
    float* dinv = ws;                               // 32000
    float* bufA = dinv + TOTALN;                    // feat A (bf16 lives here)
    float* bufB = bufA + (long)TOTALN * 128;        // feat B / p1 alias
    float* hg   = bufB + (long)TOTALN * 128;        // 4096
    float* h1   = hg + 32 * 128;                    // 6144
    float* h2   = h1 + 32 * 192;                    // 6144
    float* csr_w = h2 + 32 * 192;                   // 512000
    float* pp   = csr_w + NE;                       // 102400
    float* hgT  = pp + NB * PCH * 128;              // 4096
    unsigned short* hgB = (unsigned short*)(hgT + 128 * NB);  // 4096 bf16 (2048 f)
    int* cnt    = (int*)(hgB + 4096);               // 32000
    int* rowptr = cnt + TOTALN;                     // 32001 (+3 pad)
    int* cursor = rowptr + TOTALN + 4;              // 32000
    int* bsum   = cursor + TOTALN;                  // 128
    int* csr_src= bsum + 128;                       // 512000
    unsigned short* Wt = (unsigned short*)(csr_src + NE);  // 16384 bf16
    unsigned short* fA = (unsigned short*)bufA;
    unsigned short* fB = (unsigned short*)bufB;
    float* p1   = bufB;                             // 250*3*2048 = 1.536M floats
    float* p2   = bufA;                             // free after pool1

    // degree + norm + CSR build
    k_init_deg<<<(TOTALN + 255) / 256, 256, 0, stream>>>(dinv);
    k_deg<<<NE / 256, 256, 0, stream>>>(ei, dinv);
    k_prep<<<(TOTALN + 255) / 256, 256, 0, stream>>>(dinv, cnt);
    k_scan_block<<<125, 256, 0, stream>>>(cnt, rowptr, bsum);
    k_scan_tot<<<1, 64, 0, stream>>>(bsum);
    k_scan_add<<<125, 256, 0, stream>>>(rowptr, bsum, cursor);
    k_fill<<<NE / 256, 256, 0, stream>>>(ei, dinv, cursor, csr_src, csr_w);

    // layer 1 (x f32 -> bf16 MFMA)
    k_wcvt<<<64, 256, 0, stream>>>(Wc1, Wt);
    k_mm<1><<<500, 256, 0, stream>>>(x, Wt, fB);
    k_gather<0><<<TOTALN / 4, 256, 0, stream>>>(fB, fA, rowptr, csr_src, csr_w, dinv, bc1);
    // layer 2
    k_wcvt<<<64, 256, 0, stream>>>(Wc2, Wt);
    k_mm<0><<<500, 256, 0, stream>>>(fA, Wt, fB);
    k_gather<0><<<TOTALN / 4, 256, 0, stream>>>(fB, fA, rowptr, csr_src, csr_w, dinv, bc2);
    // layer 3 (no relu; bias folded into pool stage 2)
    k_wcvt<<<64, 256, 0, stream>>>(Wc3, Wt);
    k_mm<0><<<500, 256, 0, stream>>>(fA, Wt, fB);
    k_gather<1><<<TOTALN / 4, 256, 0, stream>>>(fB, fA, rowptr, csr_src, csr_w, dinv, nullptr);
    k_pool1<<<NB * PCH, 256, 0, stream>>>(fA, pp);
    k_pool2<<<(NB * 128 + 255) / 256, 256, 0, stream>>>(pp, bc3, hg, hgT, hgB);

    // hypernetwork + compute_q
    k_w1<<<NH * W1CH, 256, 0, stream>>>(hgB, Wg1, bg1, act, p1);
    k_red1<<<96, 256, 0, stream>>>(p1, h1);
    k_w2<<<NH * Dh, 256, 0, stream>>>(hg, Wg2, bg2, h1, p2);
    k_red2<<<24, 256, 0, stream>>>(p2, h2);
    k_out<<<NB, 192, 0, stream>>>(hg, Wg3, bg3, h2, out);
}

// Round 12
// 281.575 us; speedup vs baseline: 1.0840x; 1.0094x over previous
//
#include <hip/hip_runtime.h>
#include <hip/hip_bf16.h>
#include <math.h>

#define NB 32          // graphs
#define N_PER 1000
#define TOTALN 32000
#define NE 512000
#define HID 128
#define Dh 64
#define NH 3
#define EPSV 1e-6f
#define PCH 25         // pool chunks per graph (40 nodes each)
#define W1CH 250       // k_w1 chunks (4 n's each)

typedef __attribute__((ext_vector_type(8))) short bf16x8;
typedef __attribute__((ext_vector_type(4))) float f32x4;

__device__ __forceinline__ float softplusf(float x) {
    return fmaxf(x, 0.0f) + log1pf(expf(-fabsf(x)));
}
__device__ __forceinline__ unsigned short f2b(float f) {
    __hip_bfloat16 h = __float2bfloat16(f);
    return __builtin_bit_cast(unsigned short, h);
}
__device__ __forceinline__ float b2f(unsigned short u) {
    unsigned int x = ((unsigned int)u) << 16;
    return __builtin_bit_cast(float, x);
}

__global__ __launch_bounds__(256) void k_init_deg(float* deg) {
    int i = blockIdx.x * 256 + threadIdx.x;
    if (i < TOTALN) deg[i] = 1.0f;   // self loop
}

__global__ __launch_bounds__(256) void k_deg(const int* __restrict__ ei, float* deg) {
    int e = blockIdx.x * 256 + threadIdx.x;
    if (e < NE) atomicAdd(&deg[ei[NE + e]], 1.0f);
}

__global__ __launch_bounds__(256) void k_prep(float* __restrict__ d, int* __restrict__ cnt) {
    int i = blockIdx.x * 256 + threadIdx.x;
    if (i < TOTALN) {
        float v = d[i];
        cnt[i] = (int)v - 1;
        d[i] = rsqrtf(v);
    }
}

__global__ __launch_bounds__(256) void k_scan_block(const int* __restrict__ cnt,
                                                    int* __restrict__ rowptr,
                                                    int* __restrict__ bsum) {
    __shared__ int sh[256];
    int t = threadIdx.x;
    int i = blockIdx.x * 256 + t;
    int v = cnt[i];
    sh[t] = v;
    __syncthreads();
    for (int off = 1; off < 256; off <<= 1) {
        int add = (t >= off) ? sh[t - off] : 0;
        __syncthreads();
        sh[t] += add;
        __syncthreads();
    }
    rowptr[i] = sh[t] - v;
    if (t == 255) bsum[blockIdx.x] = sh[255];
}

__global__ void k_scan_tot(int* __restrict__ bsum) {
    if (threadIdx.x == 0) {
        int run = 0;
        for (int i = 0; i < 125; ++i) { int t = bsum[i]; bsum[i] = run; run += t; }
    }
}

__global__ __launch_bounds__(256) void k_scan_add(int* __restrict__ rowptr,
                                                  const int* __restrict__ bsum,
                                                  int* __restrict__ cursor) {
    int i = blockIdx.x * 256 + threadIdx.x;
    int v = rowptr[i] + bsum[blockIdx.x];
    rowptr[i] = v;
    cursor[i] = v;
    if (i == 0) rowptr[TOTALN] = NE;
}

__global__ __launch_bounds__(256) void k_fill(const int* __restrict__ ei,
                                              const float* __restrict__ dinv,
                                              int* __restrict__ cursor,
                                              int* __restrict__ csr_src,
                                              float* __restrict__ csr_w) {
    int e = blockIdx.x * 256 + threadIdx.x;
    if (e < NE) {
        int s = ei[e], d = ei[NE + e];
        int pos = atomicAdd(&cursor[d], 1);
        csr_src[pos] = s;
        csr_w[pos] = dinv[s] * dinv[d];
    }
}

// transpose+convert W[128][128] f32 -> Wt[c][k] bf16
__global__ __launch_bounds__(256) void k_wcvt(const float* __restrict__ W,
                                              unsigned short* __restrict__ Wt) {
    int i = blockIdx.x * 256 + threadIdx.x;   // 16384
    int k = i >> 7, c = i & 127;
    Wt[c * 128 + k] = f2b(W[i]);
}

// Y[32000 x 128](bf16) = X[32000 x 128] @ W ; MFMA 16x16x32 bf16, no LDS.
template<int INF32>
__global__ __launch_bounds__(256) void k_mm(const void* __restrict__ Xv,
                                            const unsigned short* __restrict__ Wt,
                                            unsigned short* __restrict__ Y) {
    int tid = threadIdx.x;
    int wv = tid >> 6, l = tid & 63;
    int row0 = blockIdx.x * 64 + wv * 16;
    int r = l & 15, kc = l >> 4;
    bf16x8 a[4];
    if (INF32) {
        const float* X = (const float*)Xv;
#pragma unroll
        for (int ks = 0; ks < 4; ++ks) {
            const float* p = X + (long)(row0 + r) * 128 + ks * 32 + kc * 8;
            float4 f0 = *(const float4*)p;
            float4 f1 = *(const float4*)(p + 4);
            bf16x8 t;
            t[0] = (short)f2b(f0.x); t[1] = (short)f2b(f0.y);
            t[2] = (short)f2b(f0.z); t[3] = (short)f2b(f0.w);
            t[4] = (short)f2b(f1.x); t[5] = (short)f2b(f1.y);
            t[6] = (short)f2b(f1.z); t[7] = (short)f2b(f1.w);
            a[ks] = t;
        }
    } else {
        const unsigned short* X = (const unsigned short*)Xv;
#pragma unroll
        for (int ks = 0; ks < 4; ++ks)
            a[ks] = *(const bf16x8*)(X + (long)(row0 + r) * 128 + ks * 32 + kc * 8);
    }
    f32x4 acc[8];
#pragma unroll
    for (int nt = 0; nt < 8; ++nt) acc[nt] = (f32x4){0.f, 0.f, 0.f, 0.f};
#pragma unroll
    for (int ks = 0; ks < 4; ++ks) {
#pragma unroll
        for (int nt = 0; nt < 8; ++nt) {
            bf16x8 b = *(const bf16x8*)(Wt + (nt * 16 + r) * 128 + ks * 32 + kc * 8);
            acc[nt] = __builtin_amdgcn_mfma_f32_16x16x32_bf16(a[ks], b, acc[nt], 0, 0, 0);
        }
    }
#pragma unroll
    for (int nt = 0; nt < 8; ++nt)
#pragma unroll
        for (int j = 0; j < 4; ++j)
            Y[(long)(row0 + kc * 4 + j) * 128 + nt * 16 + r] = f2b(acc[nt][j]);
}

// CSR gather on bf16 features: 1 wave per node, 4B per lane, 4-deep ILP.
template<int MODE>
__global__ __launch_bounds__(256) void k_gather(const unsigned short* __restrict__ feat,
                                                unsigned short* __restrict__ out,
                                                const int* __restrict__ rowptr,
                                                const int* __restrict__ csr_src,
                                                const float* __restrict__ csr_w,
                                                const float* __restrict__ dinv,
                                                const float* __restrict__ bias) {
    int wid = threadIdx.x >> 6, lane = threadIdx.x & 63;
    int v = blockIdx.x * 4 + wid;
    const unsigned int* f2 = (const unsigned int*)feat;
    float dv = dinv[v];
    unsigned int sv = f2[v * 64 + lane];
    float acc0 = b2f((unsigned short)(sv & 0xffff)) * dv * dv;
    float acc1 = b2f((unsigned short)(sv >> 16)) * dv * dv;
    int e = rowptr[v], e1 = rowptr[v + 1];
    for (; e + 4 <= e1; e += 4) {
        int s0 = csr_src[e], s1 = csr_src[e + 1], s2 = csr_src[e + 2], s3 = csr_src[e + 3];
        float w0 = csr_w[e], w1 = csr_w[e + 1], w2 = csr_w[e + 2], w3 = csr_w[e + 3];
        unsigned int u0 = f2[s0 * 64 + lane];
        unsigned int u1 = f2[s1 * 64 + lane];
        unsigned int u2 = f2[s2 * 64 + lane];
        unsigned int u3 = f2[s3 * 64 + lane];
        acc0 += b2f((unsigned short)(u0 & 0xffff)) * w0 + b2f((unsigned short)(u1 & 0xffff)) * w1
              + b2f((unsigned short)(u2 & 0xffff)) * w2 + b2f((unsigned short)(u3 & 0xffff)) * w3;
        acc1 += b2f((unsigned short)(u0 >> 16)) * w0 + b2f((unsigned short)(u1 >> 16)) * w1
              + b2f((unsigned short)(u2 >> 16)) * w2 + b2f((unsigned short)(u3 >> 16)) * w3;
    }
    for (; e < e1; ++e) {
        int s = csr_src[e];
        float w = csr_w[e];
        unsigned int u = f2[s * 64 + lane];
        acc0 += b2f((unsigned short)(u & 0xffff)) * w;
        acc1 += b2f((unsigned short)(u >> 16)) * w;
    }
    if (MODE == 0) {
        int c = lane * 2;
        acc0 = fmaxf(acc0 + bias[c], 0.f);
        acc1 = fmaxf(acc1 + bias[c + 1], 0.f);
    }
    ((unsigned int*)out)[v * 64 + lane] =
        (unsigned int)f2b(acc0) | ((unsigned int)f2b(acc1) << 16);
}

// pool stage 1 (bf16 input)
__global__ __launch_bounds__(256) void k_pool1(const unsigned short* __restrict__ A,
                                               float* __restrict__ pp) {
    __shared__ float sh[256];
    int b = blockIdx.x / PCH, ch = blockIdx.x % PCH;
    int c = threadIdx.x & 127, half = threadIdx.x >> 7;
    float acc = 0.f;
    int n0 = ch * 40;
#pragma unroll 4
    for (int j = half; j < 40; j += 2)
        acc += b2f(A[(long)(b * N_PER + n0 + j) * 128 + c]);
    sh[threadIdx.x] = acc;
    __syncthreads();
    if (threadIdx.x < 128)
        pp[blockIdx.x * 128 + c] = sh[c] + sh[128 + c];
}

// pool stage 2: mean + layer-3 bias; writes hg (f32), hgT (f32) and hgB (bf16)
__global__ __launch_bounds__(256) void k_pool2(const float* __restrict__ pp,
                                               const float* __restrict__ bias,
                                               float* __restrict__ hg,
                                               float* __restrict__ hgT,
                                               unsigned short* __restrict__ hgB) {
    int i = blockIdx.x * 256 + threadIdx.x;
    if (i >= NB * 128) return;
    int b = i >> 7, c = i & 127;
    float s = 0.f;
#pragma unroll
    for (int ch = 0; ch < PCH; ++ch)
        s += pp[(b * PCH + ch) * 128 + c];
    float v = s * (1.0f / N_PER) + bias[c];
    hg[i] = v;
    hgT[c * NB + b] = v;
    hgB[i] = f2b(v);
}

// k_w1 (MFMA, barrier-free): block = (h, chunk of 4 n); wave = one n (64 d-cols),
// fully independent — NO LDS, NO __syncthreads. Each wave computes
// C[32 b x 64 d] = hg @ Wg1[:, h,n,:], applies softplus(+bg1)*act, and stores
// its own per-n partial p1[(h*1000+n)][b][d]. k_red1 does the n-sum.
__global__ __launch_bounds__(256) void k_w1(const unsigned short* __restrict__ hgB,
                                            const float* __restrict__ Wg1,
                                            const float* __restrict__ bg1,
                                            const float* __restrict__ actions,
                                            float* __restrict__ p1) {
    int h = blockIdx.x / W1CH, chunk = blockIdx.x % W1CH;
    int tid = threadIdx.x;
    int wv = tid >> 6, l = tid & 63;
    int r = l & 15, kc = l >> 4;
    int n = chunk * 4 + wv;
    const long KS = (long)NH * N_PER * Dh;            // 192000
    long colbase = (long)h * (N_PER * Dh) + (long)n * Dh;
    bf16x8 a[2][4];
#pragma unroll
    for (int mt = 0; mt < 2; ++mt)
#pragma unroll
        for (int ks = 0; ks < 4; ++ks)
            a[mt][ks] = *(const bf16x8*)(hgB + (mt * 16 + r) * 128 + ks * 32 + kc * 8);
    f32x4 acc[2][4];
#pragma unroll
    for (int mt = 0; mt < 2; ++mt)
#pragma unroll
        for (int ct = 0; ct < 4; ++ct) acc[mt][ct] = (f32x4){0.f, 0.f, 0.f, 0.f};
#pragma unroll
    for (int ct = 0; ct < 4; ++ct) {
        const float* Wp = Wg1 + colbase + ct * 16 + r;
#pragma unroll
        for (int ks = 0; ks < 4; ++ks) {
            int kb = ks * 32 + kc * 8;
            float f0 = Wp[(long)(kb + 0) * KS];
            float f1 = Wp[(long)(kb + 1) * KS];
            float f2v = Wp[(long)(kb + 2) * KS];
            float f3 = Wp[(long)(kb + 3) * KS];
            float f4 = Wp[(long)(kb + 4) * KS];
            float f5 = Wp[(long)(kb + 5) * KS];
            float f6 = Wp[(long)(kb + 6) * KS];
            float f7 = Wp[(long)(kb + 7) * KS];
            bf16x8 bb;
            bb[0] = (short)f2b(f0); bb[1] = (short)f2b(f1);
            bb[2] = (short)f2b(f2v); bb[3] = (short)f2b(f3);
            bb[4] = (short)f2b(f4); bb[5] = (short)f2b(f5);
            bb[6] = (short)f2b(f6); bb[7] = (short)f2b(f7);
            acc[0][ct] = __builtin_amdgcn_mfma_f32_16x16x32_bf16(a[0][ks], bb, acc[0][ct], 0, 0, 0);
            acc[1][ct] = __builtin_amdgcn_mfma_f32_16x16x32_bf16(a[1][ks], bb, acc[1][ct], 0, 0, 0);
        }
    }
    // epilogue: softplus(+bg1) * action, direct coalesced store of this n's slab
    float actv[2][4];
#pragma unroll
    for (int mt = 0; mt < 2; ++mt)
#pragma unroll
        for (int j = 0; j < 4; ++j)
            actv[mt][j] = actions[(mt * 16 + kc * 4 + j) * N_PER + n];
    float bgv[4];
#pragma unroll
    for (int ct = 0; ct < 4; ++ct)
        bgv[ct] = bg1[colbase + ct * 16 + r];
    float* po = p1 + ((long)h * N_PER + n) * 2048;   // [b][d] slab for this n
#pragma unroll
    for (int mt = 0; mt < 2; ++mt)
#pragma unroll
        for (int ct = 0; ct < 4; ++ct)
#pragma unroll
            for (int j = 0; j < 4; ++j) {
                int b = mt * 16 + kc * 4 + j;
                int d = ct * 16 + r;
                po[b * 64 + d] = softplusf(acc[mt][ct][j] + bgv[ct]) * actv[mt][j];
            }
}

// block = (b,h): 96 blocks; thread = (part, d); sums 1000 per-n slabs (4-way split)
__global__ __launch_bounds__(256) void k_red1(const float* __restrict__ p1,
                                              float* __restrict__ h1) {
    __shared__ float sh[4][64];
    int b = blockIdx.x / 3, h = blockIdx.x % 3;
    int part = threadIdx.x >> 6, d = threadIdx.x & 63;
    const float* base = p1 + (long)h * N_PER * 2048 + b * 64 + d;
    float s = 0.f;
#pragma unroll 4
    for (int n = part; n < N_PER; n += 4)
        s += base[(long)n * 2048];
    if (part) sh[part][d] = s;
    __syncthreads();
    if (part == 0)
        h1[(b * 3 + h) * 64 + d] = sqrtf(fmaxf(s + sh[1][d] + sh[2][d] + sh[3][d], 0.f) + EPSV);
}

__global__ __launch_bounds__(256) void k_w2(const float* __restrict__ hg,
                                            const float* __restrict__ Wg2,
                                            const float* __restrict__ bg2,
                                            const float* __restrict__ h1,
                                            float* __restrict__ p2) {
    __shared__ float hgs[32][128];
    __shared__ float wt[128][64];
    __shared__ float h1s[32];
    int hd = blockIdx.x;
    int tid = threadIdx.x;
    for (int i = 0; i < 16; ++i) {
        int idx = tid + i * 256;
        hgs[idx >> 7][idx & 127] = hg[idx];
    }
    long base = (long)hd * 64;
    for (int i = 0; i < 32; ++i) {
        int idx = tid + i * 256;
        wt[idx >> 6][idx & 63] = Wg2[(long)(idx >> 6) * (NH * Dh * Dh) + base + (idx & 63)];
    }
    int h = hd >> 6, d = hd & 63;
    if (tid < 32) h1s[tid] = h1[tid * (NH * Dh) + h * Dh + d];
    __syncthreads();
    int e = tid & 63, bq = tid >> 6;
    float bgv = bg2[base + e];
    float dot[8];
#pragma unroll
    for (int bi = 0; bi < 8; ++bi) dot[bi] = 0.f;
    for (int k = 0; k < 128; ++k) {
        float w = wt[k][e];
#pragma unroll
        for (int bi = 0; bi < 8; ++bi)
            dot[bi] += hgs[bq * 8 + bi][k] * w;
    }
    float* po = p2 + (long)hd * (32 * 64);
#pragma unroll
    for (int bi = 0; bi < 8; ++bi) {
        int b = bq * 8 + bi;
        po[b * 64 + e] = softplusf(dot[bi] + bgv) * h1s[b];
    }
}

__global__ __launch_bounds__(256) void k_red2(const float* __restrict__ p2,
                                              float* __restrict__ h2) {
    int o = blockIdx.x * 256 + threadIdx.x;
    if (o >= 32 * 192) return;
    int bh = o >> 6;
    int h = bh % 3, b = bh / 3;
    int e = o & 63;
    float s = 0.f;
    for (int d = 0; d < 64; ++d)
        s += p2[(h * 64 + d) * 2048 + b * 64 + e];
    h2[o] = log1pf(fmaxf(s, 0.f));
}

__global__ __launch_bounds__(192) void k_out(const float* __restrict__ hg,
                                             const float* __restrict__ Wg3,
                                             const float* __restrict__ bg3,
                                             const float* __restrict__ h2,
                                             float* __restrict__ out) {
    __shared__ float hgb[128];
    __shared__ float hres[NH];
    int b = blockIdx.x, tid = threadIdx.x;
    if (tid < 128) hgb[tid] = hg[b * 128 + tid];
    __syncthreads();
    int h = tid / 64, e = tid & 63;
    int c = h * 64 + e;
    float dot = 0.f;
    for (int k = 0; k < 128; ++k)
        dot += hgb[k] * Wg3[k * (NH * Dh) + c];
    float v = softplusf(dot + bg3[c]) * h2[b * 192 + c];
    for (int off = 32; off; off >>= 1)
        v += __shfl_down(v, off, 64);
    if (e == 0) hres[h] = v;
    __syncthreads();
    if (tid == 0) out[b] = fminf(fminf(hres[0], hres[1]), hres[2]);
}

extern "C" void kernel_launch(void* const* d_in, const int* in_sizes, int n_in,
                              void* d_out, int out_size, void* d_ws, size_t ws_size,
                              hipStream_t stream) {
    const float* x   = (const float*)d_in[0];
    const int*   ei  = (const int*)d_in[1];
    const float* act = (const float*)d_in[3];
    const float* Wc1 = (const float*)d_in[4];
    const float* bc1 = (const float*)d_in[5];
    const float* Wc2 = (const float*)d_in[6];
    const float* bc2 = (const float*)d_in[7];
    const float* Wc3 = (const float*)d_in[8];
    const float* bc3 = (const float*)d_in[9];
    const float* Wg1 = (const float*)d_in[10];
    const float* bg1 = (const float*)d_in[11];
    const float* Wg2 = (const float*)d_in[12];
    const float* bg2 = (const float*)d_in[13];
    const float* Wg3 = (const float*)d_in[14];
    const float* bg3 = (const float*)d_in[15];
    float* out = (float*)d_out;

    float* ws   = (float*)d_ws;
    float* dinv = ws;                               // 32000
    float* bufA = dinv + TOTALN;                    // feat A (bf16) / p1 lower
    float* bufB = bufA + (long)TOTALN * 128;        // feat B / p1 upper
    float* hg   = bufB + (long)TOTALN * 128;        // 4096
    float* h1   = hg + 32 * 128;                    // 6144
    float* h2   = h1 + 32 * 192;                    // 6144
    float* csr_w = h2 + 32 * 192;                   // 512000
    float* pp   = csr_w + NE;                       // 102400
    float* hgT  = pp + NB * PCH * 128;              // 4096
    unsigned short* hgB = (unsigned short*)(hgT + 128 * NB);  // 4096 bf16
    int* cnt    = (int*)(hgB + 4096);               // 32000
    int* rowptr = cnt + TOTALN;                     // 32001 (+3 pad)
    int* cursor = rowptr + TOTALN + 4;              // 32000
    int* bsum   = cursor + TOTALN;                  // 128
    int* csr_src= bsum + 128;                       // 512000
    unsigned short* Wt = (unsigned short*)(csr_src + NE);  // 16384 bf16
    unsigned short* fA = (unsigned short*)bufA;
    unsigned short* fB = (unsigned short*)bufB;
    // p1 spans bufA+bufB (3*1000*2048 = 6.144M floats <= 8.192M combined);
    // both are free once pool1/pool2 complete. p2 tucked after p1.
    float* p1   = bufA;
    float* p2   = bufA + (long)3 * N_PER * 2048;    // +393216 <= 8.192M total

    // degree + norm + CSR build
    k_init_deg<<<(TOTALN + 255) / 256, 256, 0, stream>>>(dinv);
    k_deg<<<NE / 256, 256, 0, stream>>>(ei, dinv);
    k_prep<<<(TOTALN + 255) / 256, 256, 0, stream>>>(dinv, cnt);
    k_scan_block<<<125, 256, 0, stream>>>(cnt, rowptr, bsum);
    k_scan_tot<<<1, 64, 0, stream>>>(bsum);
    k_scan_add<<<125, 256, 0, stream>>>(rowptr, bsum, cursor);
    k_fill<<<NE / 256, 256, 0, stream>>>(ei, dinv, cursor, csr_src, csr_w);

    // layer 1 (x f32 -> bf16 MFMA)
    k_wcvt<<<64, 256, 0, stream>>>(Wc1, Wt);
    k_mm<1><<<500, 256, 0, stream>>>(x, Wt, fB);
    k_gather<0><<<TOTALN / 4, 256, 0, stream>>>(fB, fA, rowptr, csr_src, csr_w, dinv, bc1);
    // layer 2
    k_wcvt<<<64, 256, 0, stream>>>(Wc2, Wt);
    k_mm<0><<<500, 256, 0, stream>>>(fA, Wt, fB);
    k_gather<0><<<TOTALN / 4, 256, 0, stream>>>(fB, fA, rowptr, csr_src, csr_w, dinv, bc2);
    // layer 3 (no relu; bias folded into pool stage 2)
    k_wcvt<<<64, 256, 0, stream>>>(Wc3, Wt);
    k_mm<0><<<500, 256, 0, stream>>>(fA, Wt, fB);
    k_gather<1><<<TOTALN / 4, 256, 0, stream>>>(fB, fA, rowptr, csr_src, csr_w, dinv, nullptr);
    k_pool1<<<NB * PCH, 256, 0, stream>>>(fA, pp);
    k_pool2<<<(NB * 128 + 255) / 256, 256, 0, stream>>>(pp, bc3, hg, hgT, hgB);

    // hypernetwork + compute_q
    k_w1<<<NH * W1CH, 256, 0, stream>>>(hgB, Wg1, bg1, act, p1);
    k_red1<<<96, 256, 0, stream>>>(p1, h1);
    k_w2<<<NH * Dh, 256, 0, stream>>>(hg, Wg2, bg2, h1, p2);
    k_red2<<<24, 256, 0, stream>>>(p2, h2);
    k_out<<<NB, 192, 0, stream>>>(hg, Wg3, bg3, h2, out);
}

// Round 13
// 270.903 us; speedup vs baseline: 1.1267x; 1.0394x over previous
//
#include <hip/hip_runtime.h>
#include <hip/hip_bf16.h>
#include <math.h>

#define NB 32          // graphs
#define N_PER 1000
#define TOTALN 32000
#define NE 512000
#define HID 128
#define Dh 64
#define NH 3
#define EPSV 1e-6f
#define PCH 25         // pool chunks per graph (40 nodes each)
#define W1CH 250       // k_w1 chunks (4 n's each)

typedef __attribute__((ext_vector_type(8))) short bf16x8;
typedef __attribute__((ext_vector_type(4))) float f32x4;

__device__ __forceinline__ float softplusf(float x) {
    return fmaxf(x, 0.0f) + log1pf(expf(-fabsf(x)));
}
__device__ __forceinline__ unsigned short f2b(float f) {
    __hip_bfloat16 h = __float2bfloat16(f);
    return __builtin_bit_cast(unsigned short, h);
}
__device__ __forceinline__ float b2f(unsigned short u) {
    unsigned int x = ((unsigned int)u) << 16;
    return __builtin_bit_cast(float, x);
}

__global__ __launch_bounds__(256) void k_init_deg(float* deg) {
    int i = blockIdx.x * 256 + threadIdx.x;
    if (i < TOTALN) deg[i] = 1.0f;   // self loop
}

__global__ __launch_bounds__(256) void k_deg(const int* __restrict__ ei, float* deg) {
    int e = blockIdx.x * 256 + threadIdx.x;
    if (e < NE) atomicAdd(&deg[ei[NE + e]], 1.0f);
}

__global__ __launch_bounds__(256) void k_prep(float* __restrict__ d, int* __restrict__ cnt) {
    int i = blockIdx.x * 256 + threadIdx.x;
    if (i < TOTALN) {
        float v = d[i];
        cnt[i] = (int)v - 1;
        d[i] = rsqrtf(v);
    }
}

__global__ __launch_bounds__(256) void k_scan_block(const int* __restrict__ cnt,
                                                    int* __restrict__ rowptr,
                                                    int* __restrict__ bsum) {
    __shared__ int sh[256];
    int t = threadIdx.x;
    int i = blockIdx.x * 256 + t;
    int v = cnt[i];
    sh[t] = v;
    __syncthreads();
    for (int off = 1; off < 256; off <<= 1) {
        int add = (t >= off) ? sh[t - off] : 0;
        __syncthreads();
        sh[t] += add;
        __syncthreads();
    }
    rowptr[i] = sh[t] - v;
    if (t == 255) bsum[blockIdx.x] = sh[255];
}

__global__ void k_scan_tot(int* __restrict__ bsum) {
    if (threadIdx.x == 0) {
        int run = 0;
        for (int i = 0; i < 125; ++i) { int t = bsum[i]; bsum[i] = run; run += t; }
    }
}

__global__ __launch_bounds__(256) void k_scan_add(int* __restrict__ rowptr,
                                                  const int* __restrict__ bsum,
                                                  int* __restrict__ cursor) {
    int i = blockIdx.x * 256 + threadIdx.x;
    int v = rowptr[i] + bsum[blockIdx.x];
    rowptr[i] = v;
    cursor[i] = v;
    if (i == 0) rowptr[TOTALN] = NE;
}

__global__ __launch_bounds__(256) void k_fill(const int* __restrict__ ei,
                                              const float* __restrict__ dinv,
                                              int* __restrict__ cursor,
                                              int* __restrict__ csr_src,
                                              float* __restrict__ csr_w) {
    int e = blockIdx.x * 256 + threadIdx.x;
    if (e < NE) {
        int s = ei[e], d = ei[NE + e];
        int pos = atomicAdd(&cursor[d], 1);
        csr_src[pos] = s;
        csr_w[pos] = dinv[s] * dinv[d];
    }
}

// transpose+convert W[128][128] f32 -> Wt[c][k] bf16
__global__ __launch_bounds__(256) void k_wcvt(const float* __restrict__ W,
                                              unsigned short* __restrict__ Wt) {
    int i = blockIdx.x * 256 + threadIdx.x;   // 16384
    int k = i >> 7, c = i & 127;
    Wt[c * 128 + k] = f2b(W[i]);
}

// Y[32000 x 128](bf16) = X[32000 x 128] @ W ; MFMA 16x16x32 bf16, no LDS.
template<int INF32>
__global__ __launch_bounds__(256) void k_mm(const void* __restrict__ Xv,
                                            const unsigned short* __restrict__ Wt,
                                            unsigned short* __restrict__ Y) {
    int tid = threadIdx.x;
    int wv = tid >> 6, l = tid & 63;
    int row0 = blockIdx.x * 64 + wv * 16;
    int r = l & 15, kc = l >> 4;
    bf16x8 a[4];
    if (INF32) {
        const float* X = (const float*)Xv;
#pragma unroll
        for (int ks = 0; ks < 4; ++ks) {
            const float* p = X + (long)(row0 + r) * 128 + ks * 32 + kc * 8;
            float4 f0 = *(const float4*)p;
            float4 f1 = *(const float4*)(p + 4);
            bf16x8 t;
            t[0] = (short)f2b(f0.x); t[1] = (short)f2b(f0.y);
            t[2] = (short)f2b(f0.z); t[3] = (short)f2b(f0.w);
            t[4] = (short)f2b(f1.x); t[5] = (short)f2b(f1.y);
            t[6] = (short)f2b(f1.z); t[7] = (short)f2b(f1.w);
            a[ks] = t;
        }
    } else {
        const unsigned short* X = (const unsigned short*)Xv;
#pragma unroll
        for (int ks = 0; ks < 4; ++ks)
            a[ks] = *(const bf16x8*)(X + (long)(row0 + r) * 128 + ks * 32 + kc * 8);
    }
    f32x4 acc[8];
#pragma unroll
    for (int nt = 0; nt < 8; ++nt) acc[nt] = (f32x4){0.f, 0.f, 0.f, 0.f};
#pragma unroll
    for (int ks = 0; ks < 4; ++ks) {
#pragma unroll
        for (int nt = 0; nt < 8; ++nt) {
            bf16x8 b = *(const bf16x8*)(Wt + (nt * 16 + r) * 128 + ks * 32 + kc * 8);
            acc[nt] = __builtin_amdgcn_mfma_f32_16x16x32_bf16(a[ks], b, acc[nt], 0, 0, 0);
        }
    }
#pragma unroll
    for (int nt = 0; nt < 8; ++nt)
#pragma unroll
        for (int j = 0; j < 4; ++j)
            Y[(long)(row0 + kc * 4 + j) * 128 + nt * 16 + r] = f2b(acc[nt][j]);
}

// CSR gather on bf16 features: 1 wave per node, 4B per lane, 4-deep ILP.
template<int MODE>
__global__ __launch_bounds__(256) void k_gather(const unsigned short* __restrict__ feat,
                                                unsigned short* __restrict__ out,
                                                const int* __restrict__ rowptr,
                                                const int* __restrict__ csr_src,
                                                const float* __restrict__ csr_w,
                                                const float* __restrict__ dinv,
                                                const float* __restrict__ bias) {
    int wid = threadIdx.x >> 6, lane = threadIdx.x & 63;
    int v = blockIdx.x * 4 + wid;
    const unsigned int* f2 = (const unsigned int*)feat;
    float dv = dinv[v];
    unsigned int sv = f2[v * 64 + lane];
    float acc0 = b2f((unsigned short)(sv & 0xffff)) * dv * dv;
    float acc1 = b2f((unsigned short)(sv >> 16)) * dv * dv;
    int e = rowptr[v], e1 = rowptr[v + 1];
    for (; e + 4 <= e1; e += 4) {
        int s0 = csr_src[e], s1 = csr_src[e + 1], s2 = csr_src[e + 2], s3 = csr_src[e + 3];
        float w0 = csr_w[e], w1 = csr_w[e + 1], w2 = csr_w[e + 2], w3 = csr_w[e + 3];
        unsigned int u0 = f2[s0 * 64 + lane];
        unsigned int u1 = f2[s1 * 64 + lane];
        unsigned int u2 = f2[s2 * 64 + lane];
        unsigned int u3 = f2[s3 * 64 + lane];
        acc0 += b2f((unsigned short)(u0 & 0xffff)) * w0 + b2f((unsigned short)(u1 & 0xffff)) * w1
              + b2f((unsigned short)(u2 & 0xffff)) * w2 + b2f((unsigned short)(u3 & 0xffff)) * w3;
        acc1 += b2f((unsigned short)(u0 >> 16)) * w0 + b2f((unsigned short)(u1 >> 16)) * w1
              + b2f((unsigned short)(u2 >> 16)) * w2 + b2f((unsigned short)(u3 >> 16)) * w3;
    }
    for (; e < e1; ++e) {
        int s = csr_src[e];
        float w = csr_w[e];
        unsigned int u = f2[s * 64 + lane];
        acc0 += b2f((unsigned short)(u & 0xffff)) * w;
        acc1 += b2f((unsigned short)(u >> 16)) * w;
    }
    if (MODE == 0) {
        int c = lane * 2;
        acc0 = fmaxf(acc0 + bias[c], 0.f);
        acc1 = fmaxf(acc1 + bias[c + 1], 0.f);
    }
    ((unsigned int*)out)[v * 64 + lane] =
        (unsigned int)f2b(acc0) | ((unsigned int)f2b(acc1) << 16);
}

// pool stage 1 (bf16 input)
__global__ __launch_bounds__(256) void k_pool1(const unsigned short* __restrict__ A,
                                               float* __restrict__ pp) {
    __shared__ float sh[256];
    int b = blockIdx.x / PCH, ch = blockIdx.x % PCH;
    int c = threadIdx.x & 127, half = threadIdx.x >> 7;
    float acc = 0.f;
    int n0 = ch * 40;
#pragma unroll 4
    for (int j = half; j < 40; j += 2)
        acc += b2f(A[(long)(b * N_PER + n0 + j) * 128 + c]);
    sh[threadIdx.x] = acc;
    __syncthreads();
    if (threadIdx.x < 128)
        pp[blockIdx.x * 128 + c] = sh[c] + sh[128 + c];
}

// pool stage 2: mean + layer-3 bias; writes hg (f32), hgT (f32) and hgB (bf16)
__global__ __launch_bounds__(256) void k_pool2(const float* __restrict__ pp,
                                               const float* __restrict__ bias,
                                               float* __restrict__ hg,
                                               float* __restrict__ hgT,
                                               unsigned short* __restrict__ hgB) {
    int i = blockIdx.x * 256 + threadIdx.x;
    if (i >= NB * 128) return;
    int b = i >> 7, c = i & 127;
    float s = 0.f;
#pragma unroll
    for (int ch = 0; ch < PCH; ++ch)
        s += pp[(b * PCH + ch) * 128 + c];
    float v = s * (1.0f / N_PER) + bias[c];
    hg[i] = v;
    hgT[c * NB + b] = v;
    hgB[i] = f2b(v);
}

// k_w1 (MFMA + LDS-coalesced staging): block = (h, chunk of 4 n); 4 waves.
// Per n: stage Wg1 column [128k x 64d] COALESCED (256B d-rows) into LDS as
// bf16 wt[d][k] (rows padded to 136 shorts = 16B-aligned), then each wave
// computes its 16-d slice: B-frag = ds_read_b128 of 8 consecutive k.
// Epilogue softplus(+bg1)*act -> per-n slab p1[(h,n)][b][d]; k_red1 sums n.
__global__ __launch_bounds__(256) void k_w1(const unsigned short* __restrict__ hgB,
                                            const float* __restrict__ Wg1,
                                            const float* __restrict__ bg1,
                                            const float* __restrict__ actions,
                                            float* __restrict__ p1) {
    __shared__ unsigned short wt[64][136];   // [d][k], pad 128->136 (16B-aligned rows)
    int h = blockIdx.x / W1CH, chunk = blockIdx.x % W1CH;
    int tid = threadIdx.x;
    int wv = tid >> 6, l = tid & 63;
    int r = l & 15, kc = l >> 4;
    const long KS = (long)NH * N_PER * Dh;            // 192000
    // A frags from hgB (L2-hot), same for all waves
    bf16x8 a[2][4];
#pragma unroll
    for (int mt = 0; mt < 2; ++mt)
#pragma unroll
        for (int ks = 0; ks < 4; ++ks)
            a[mt][ks] = *(const bf16x8*)(hgB + (mt * 16 + r) * 128 + ks * 32 + kc * 8);
    int sd = tid & 63, sk = tid >> 6;   // staging: (d=sd, k = it*4+sk)
    for (int nn = 0; nn < 4; ++nn) {
        int n = chunk * 4 + nn;
        long colbase = (long)h * (N_PER * Dh) + (long)n * Dh;
        __syncthreads();   // previous compute done before overwrite
        const float* Wb = Wg1 + colbase + sd;
#pragma unroll 8
        for (int it = 0; it < 32; ++it) {
            int k = it * 4 + sk;
            wt[sd][k] = f2b(Wb[(long)k * KS]);   // global read coalesced along d
        }
        __syncthreads();
        f32x4 acc0 = (f32x4){0.f, 0.f, 0.f, 0.f};
        f32x4 acc1 = (f32x4){0.f, 0.f, 0.f, 0.f};
#pragma unroll
        for (int ks = 0; ks < 4; ++ks) {
            bf16x8 bb = *(const bf16x8*)&wt[wv * 16 + r][ks * 32 + kc * 8];
            acc0 = __builtin_amdgcn_mfma_f32_16x16x32_bf16(a[0][ks], bb, acc0, 0, 0, 0);
            acc1 = __builtin_amdgcn_mfma_f32_16x16x32_bf16(a[1][ks], bb, acc1, 0, 0, 0);
        }
        // epilogue: wave wv owns cols d = wv*16 + r
        float bgv = bg1[colbase + wv * 16 + r];
        float* po = p1 + ((long)h * N_PER + n) * 2048;
#pragma unroll
        for (int j = 0; j < 4; ++j) {
            int b0 = kc * 4 + j;
            int b1 = 16 + kc * 4 + j;
            po[b0 * 64 + wv * 16 + r] = softplusf(acc0[j] + bgv) * actions[b0 * N_PER + n];
            po[b1 * 64 + wv * 16 + r] = softplusf(acc1[j] + bgv) * actions[b1 * N_PER + n];
        }
    }
}

// red1 stage A: grid 96*8; block = (bh, seg of 125 n); 4 part x 64 d
__global__ __launch_bounds__(256) void k_red1a(const float* __restrict__ p1,
                                               float* __restrict__ rp) {
    __shared__ float sh[4][64];
    int bh = blockIdx.x >> 3, seg = blockIdx.x & 7;   // bh = b*3+h
    int b = bh / 3, h = bh % 3;
    int part = threadIdx.x >> 6, d = threadIdx.x & 63;
    const float* base = p1 + (long)h * N_PER * 2048 + b * 64 + d;
    float s = 0.f;
    for (int n = seg * 125 + part; n < seg * 125 + 125; n += 4)
        s += base[(long)n * 2048];
    if (part) sh[part][d] = s;
    __syncthreads();
    if (part == 0)
        rp[((long)bh * 8 + seg) * 64 + d] = s + sh[1][d] + sh[2][d] + sh[3][d];
}

// red1 stage B: 96*64 outputs; sum 8 segs + SafeSqrt
__global__ __launch_bounds__(256) void k_red1b(const float* __restrict__ rp,
                                               float* __restrict__ h1) {
    int o = blockIdx.x * 256 + threadIdx.x;
    if (o >= 96 * 64) return;
    int bh = o >> 6, d = o & 63;
    float s = 0.f;
#pragma unroll
    for (int seg = 0; seg < 8; ++seg)
        s += rp[((long)bh * 8 + seg) * 64 + d];
    h1[bh * 64 + d] = sqrtf(fmaxf(s, 0.f) + EPSV);
}

__global__ __launch_bounds__(256) void k_w2(const float* __restrict__ hg,
                                            const float* __restrict__ Wg2,
                                            const float* __restrict__ bg2,
                                            const float* __restrict__ h1,
                                            float* __restrict__ p2) {
    __shared__ float hgs[32][128];
    __shared__ float wt[128][64];
    __shared__ float h1s[32];
    int hd = blockIdx.x;
    int tid = threadIdx.x;
    for (int i = 0; i < 16; ++i) {
        int idx = tid + i * 256;
        hgs[idx >> 7][idx & 127] = hg[idx];
    }
    long base = (long)hd * 64;
    for (int i = 0; i < 32; ++i) {
        int idx = tid + i * 256;
        wt[idx >> 6][idx & 63] = Wg2[(long)(idx >> 6) * (NH * Dh * Dh) + base + (idx & 63)];
    }
    int h = hd >> 6, d = hd & 63;
    if (tid < 32) h1s[tid] = h1[tid * (NH * Dh) + h * Dh + d];
    __syncthreads();
    int e = tid & 63, bq = tid >> 6;
    float bgv = bg2[base + e];
    float dot[8];
#pragma unroll
    for (int bi = 0; bi < 8; ++bi) dot[bi] = 0.f;
    for (int k = 0; k < 128; ++k) {
        float w = wt[k][e];
#pragma unroll
        for (int bi = 0; bi < 8; ++bi)
            dot[bi] += hgs[bq * 8 + bi][k] * w;
    }
    float* po = p2 + (long)hd * (32 * 64);
#pragma unroll
    for (int bi = 0; bi < 8; ++bi) {
        int b = bq * 8 + bi;
        po[b * 64 + e] = softplusf(dot[bi] + bgv) * h1s[b];
    }
}

__global__ __launch_bounds__(256) void k_red2(const float* __restrict__ p2,
                                              float* __restrict__ h2) {
    int o = blockIdx.x * 256 + threadIdx.x;
    if (o >= 32 * 192) return;
    int bh = o >> 6;
    int h = bh % 3, b = bh / 3;
    int e = o & 63;
    float s = 0.f;
    for (int d = 0; d < 64; ++d)
        s += p2[(h * 64 + d) * 2048 + b * 64 + e];
    h2[o] = log1pf(fmaxf(s, 0.f));
}

__global__ __launch_bounds__(192) void k_out(const float* __restrict__ hg,
                                             const float* __restrict__ Wg3,
                                             const float* __restrict__ bg3,
                                             const float* __restrict__ h2,
                                             float* __restrict__ out) {
    __shared__ float hgb[128];
    __shared__ float hres[NH];
    int b = blockIdx.x, tid = threadIdx.x;
    if (tid < 128) hgb[tid] = hg[b * 128 + tid];
    __syncthreads();
    int h = tid / 64, e = tid & 63;
    int c = h * 64 + e;
    float dot = 0.f;
    for (int k = 0; k < 128; ++k)
        dot += hgb[k] * Wg3[k * (NH * Dh) + c];
    float v = softplusf(dot + bg3[c]) * h2[b * 192 + c];
    for (int off = 32; off; off >>= 1)
        v += __shfl_down(v, off, 64);
    if (e == 0) hres[h] = v;
    __syncthreads();
    if (tid == 0) out[b] = fminf(fminf(hres[0], hres[1]), hres[2]);
}

extern "C" void kernel_launch(void* const* d_in, const int* in_sizes, int n_in,
                              void* d_out, int out_size, void* d_ws, size_t ws_size,
                              hipStream_t stream) {
    const float* x   = (const float*)d_in[0];
    const int*   ei  = (const int*)d_in[1];
    const float* act = (const float*)d_in[3];
    const float* Wc1 = (const float*)d_in[4];
    const float* bc1 = (const float*)d_in[5];
    const float* Wc2 = (const float*)d_in[6];
    const float* bc2 = (const float*)d_in[7];
    const float* Wc3 = (const float*)d_in[8];
    const float* bc3 = (const float*)d_in[9];
    const float* Wg1 = (const float*)d_in[10];
    const float* bg1 = (const float*)d_in[11];
    const float* Wg2 = (const float*)d_in[12];
    const float* bg2 = (const float*)d_in[13];
    const float* Wg3 = (const float*)d_in[14];
    const float* bg3 = (const float*)d_in[15];
    float* out = (float*)d_out;

    float* ws   = (float*)d_ws;
    float* dinv = ws;                               // 32000
    float* bufA = dinv + TOTALN;                    // feat A (bf16) / p1 lower
    float* bufB = bufA + (long)TOTALN * 128;        // feat B / p1 upper
    float* hg   = bufB + (long)TOTALN * 128;        // 4096
    float* h1   = hg + 32 * 128;                    // 6144
    float* h2   = h1 + 32 * 192;                    // 6144
    float* csr_w = h2 + 32 * 192;                   // 512000
    float* pp   = csr_w + NE;                       // 102400 (reused as rp for red1a)
    float* hgT  = pp + NB * PCH * 128;              // 4096
    unsigned short* hgB = (unsigned short*)(hgT + 128 * NB);  // 4096 bf16
    int* cnt    = (int*)(hgB + 4096);               // 32000
    int* rowptr = cnt + TOTALN;                     // 32001 (+3 pad)
    int* cursor = rowptr + TOTALN + 4;              // 32000
    int* bsum   = cursor + TOTALN;                  // 128
    int* csr_src= bsum + 128;                       // 512000
    unsigned short* Wt = (unsigned short*)(csr_src + NE);  // 16384 bf16
    unsigned short* fA = (unsigned short*)bufA;
    unsigned short* fB = (unsigned short*)bufB;
    // p1 spans bufA+bufB (6.144M floats <= 8.192M combined); p2 after p1.
    float* p1   = bufA;
    float* p2   = bufA + (long)3 * N_PER * 2048;
    float* rp   = pp;                               // 49152 <= 102400

    // degree + norm + CSR build
    k_init_deg<<<(TOTALN + 255) / 256, 256, 0, stream>>>(dinv);
    k_deg<<<NE / 256, 256, 0, stream>>>(ei, dinv);
    k_prep<<<(TOTALN + 255) / 256, 256, 0, stream>>>(dinv, cnt);
    k_scan_block<<<125, 256, 0, stream>>>(cnt, rowptr, bsum);
    k_scan_tot<<<1, 64, 0, stream>>>(bsum);
    k_scan_add<<<125, 256, 0, stream>>>(rowptr, bsum, cursor);
    k_fill<<<NE / 256, 256, 0, stream>>>(ei, dinv, cursor, csr_src, csr_w);

    // layer 1 (x f32 -> bf16 MFMA)
    k_wcvt<<<64, 256, 0, stream>>>(Wc1, Wt);
    k_mm<1><<<500, 256, 0, stream>>>(x, Wt, fB);
    k_gather<0><<<TOTALN / 4, 256, 0, stream>>>(fB, fA, rowptr, csr_src, csr_w, dinv, bc1);
    // layer 2
    k_wcvt<<<64, 256, 0, stream>>>(Wc2, Wt);
    k_mm<0><<<500, 256, 0, stream>>>(fA, Wt, fB);
    k_gather<0><<<TOTALN / 4, 256, 0, stream>>>(fB, fA, rowptr, csr_src, csr_w, dinv, bc2);
    // layer 3 (no relu; bias folded into pool stage 2)
    k_wcvt<<<64, 256, 0, stream>>>(Wc3, Wt);
    k_mm<0><<<500, 256, 0, stream>>>(fA, Wt, fB);
    k_gather<1><<<TOTALN / 4, 256, 0, stream>>>(fB, fA, rowptr, csr_src, csr_w, dinv, nullptr);
    k_pool1<<<NB * PCH, 256, 0, stream>>>(fA, pp);
    k_pool2<<<(NB * 128 + 255) / 256, 256, 0, stream>>>(pp, bc3, hg, hgT, hgB);

    // hypernetwork + compute_q
    k_w1<<<NH * W1CH, 256, 0, stream>>>(hgB, Wg1, bg1, act, p1);
    k_red1a<<<96 * 8, 256, 0, stream>>>(p1, rp);
    k_red1b<<<24, 256, 0, stream>>>(rp, h1);
    k_w2<<<NH * Dh, 256, 0, stream>>>(hg, Wg2, bg2, h1, p2);
    k_red2<<<24, 256, 0, stream>>>(p2, h2);
    k_out<<<NB, 192, 0, stream>>>(hg, Wg3, bg3, h2, out);
}